// Round 6
// baseline (272.120 us; speedup 1.0000x reference)
//
#include <hip/hip_runtime.h>

#define FDIM 128
#define HEADS 4
#define CD 32
#define BM 64
#define XPAD 68
#define NXCD 8

static __device__ __forceinline__ unsigned short f2bf(float v) {
    unsigned u = __float_as_uint(v);
    u += 0x7FFF + ((u >> 16) & 1);          // round-nearest-even
    return (unsigned short)(u >> 16);
}
static __device__ __forceinline__ float bf2f(unsigned short u) {
    return __uint_as_float(((unsigned)u) << 16);
}
static __device__ __forceinline__ int xcc_id() {
    int x;
    asm volatile("s_getreg_b32 %0, hwreg(HW_REG_XCC_ID)" : "=s"(x));
    return x & (NXCD - 1);
}
// XCD-local atomic add: workgroup scope keeps the RMW in the local TCC (L2)
static __device__ __forceinline__ void atomAddX(float* p, float v) {
    __hip_atomic_fetch_add(p, v, __ATOMIC_RELAXED, __HIP_MEMORY_SCOPE_WORKGROUP);
}

// K1: xwh[n][c][h] (bf16) = row-tile of x @ W. x-tile in LDS, W from L2.
__global__ __launch_bounds__(256) void k_gemm(const float* __restrict__ x,
                                              const float* __restrict__ w,
                                              unsigned short* __restrict__ xwh, int N)
{
    __shared__ float xs[FDIM * XPAD];    // [k][row]
    int t = threadIdx.x;
    int row0 = blockIdx.x * BM;
#pragma unroll
    for (int it = 0; it < 8; it++) {
        int i = t + 256 * it;
        int row = i & 63, kq = i >> 6;
        float4 v = make_float4(0.f, 0.f, 0.f, 0.f);
        if (row0 + row < N) v = ((const float4*)x)[(size_t)(row0 + row) * 32 + kq];
        xs[(kq * 4 + 0) * XPAD + row] = v.x;
        xs[(kq * 4 + 1) * XPAD + row] = v.y;
        xs[(kq * 4 + 2) * XPAD + row] = v.z;
        xs[(kq * 4 + 3) * XPAD + row] = v.w;
    }
    __syncthreads();
    int tx = t & 31, ty = t >> 5;
    int c0 = tx * 4, r0 = ty * 8;
    const float4* w4 = (const float4*)w;
    float acc[8][4];
#pragma unroll
    for (int i = 0; i < 8; i++)
#pragma unroll
        for (int j = 0; j < 4; j++) acc[i][j] = 0.f;
#pragma unroll 4
    for (int k = 0; k < FDIM; k++) {
        float4 wv = w4[k * 32 + tx];
        float4 xa = *(const float4*)&xs[k * XPAD + r0];
        float4 xb = *(const float4*)&xs[k * XPAD + r0 + 4];
        float xr[8] = {xa.x, xa.y, xa.z, xa.w, xb.x, xb.y, xb.z, xb.w};
        float wr[4] = {wv.x, wv.y, wv.z, wv.w};
#pragma unroll
        for (int i = 0; i < 8; i++)
#pragma unroll
            for (int j = 0; j < 4; j++) acc[i][j] += xr[i] * wr[j];
    }
    int h = c0 >> 5, chb = c0 & 31;
#pragma unroll
    for (int i = 0; i < 8; i++) {
        int r = row0 + r0 + i;
        if (r < N) {
#pragma unroll
            for (int j = 0; j < 4; j++)
                xwh[(size_t)r * FDIM + (chb + j) * 4 + h] = f2bf(acc[i][j]);
        }
    }
}

// K2: per-node half-logits
__global__ __launch_bounds__(256) void k_logits(const unsigned short* __restrict__ xwh,
                                                const float* __restrict__ att,
                                                float* __restrict__ a_src,
                                                float* __restrict__ a_dst, int N)
{
    __shared__ float attl[HEADS * 2 * CD];
    int t = threadIdx.x;
    attl[t] = att[t];
    __syncthreads();
    int n = blockIdx.x * 256 + t;
    if (n >= N) return;
    const ushort4* xp = (const ushort4*)(xwh + (size_t)n * FDIM);
    float s[4] = {0.f, 0.f, 0.f, 0.f}, d[4] = {0.f, 0.f, 0.f, 0.f};
#pragma unroll 8
    for (int c = 0; c < CD; c++) {
        ushort4 p = xp[c];
        float f0 = bf2f(p.x), f1 = bf2f(p.y), f2 = bf2f(p.z), f3 = bf2f(p.w);
        s[0] += f0 * attl[0 * 64 + c];  d[0] += f0 * attl[0 * 64 + 32 + c];
        s[1] += f1 * attl[1 * 64 + c];  d[1] += f1 * attl[1 * 64 + 32 + c];
        s[2] += f2 * attl[2 * 64 + c];  d[2] += f2 * attl[2 * 64 + 32 + c];
        s[3] += f3 * attl[3 * 64 + c];  d[3] += f3 * attl[3 * 64 + 32 + c];
    }
    *(float4*)&a_src[n * 4] = make_float4(s[0], s[1], s[2], s[3]);
    *(float4*)&a_dst[n * 4] = make_float4(d[0], d[1], d[2], d[3]);
}

// K3: zero seg8 + out8 (contiguous region, 8*N*36 floats)
__global__ void k_init(float4* __restrict__ z, int n4)
{
    int i = blockIdx.x * 256 + threadIdx.x;
    if (i < n4) z[i] = make_float4(0.f, 0.f, 0.f, 0.f);
}

// K4: seg8[xcd][row,h] += exp(leaky(...)); XCD-local L2 atomics
__global__ __launch_bounds__(256) void k_esum(const int* __restrict__ ei, int E,
                                              const float* __restrict__ a_src,
                                              const float* __restrict__ a_dst,
                                              float* __restrict__ seg8, int N,
                                              float* __restrict__ ealpha)
{
    int xc = xcc_id();
    float* seg = seg8 + (size_t)xc * N * HEADS;
    int gid = blockIdx.x * 256 + threadIdx.x;
    if (gid >= E * HEADS) return;
    int e = gid >> 2, h = gid & 3;
    int r = ei[e], cl = ei[E + e];
    float a = a_src[r * 4 + h] + a_dst[cl * 4 + h];
    a = a >= 0.f ? a : 0.2f * a;
    float ex = __expf(a);
    ealpha[gid] = ex;
    atomAddX(&seg[r * 4 + h], ex);
}

// K4b: inv = 1/(sum_x seg8[x] + eps)
__global__ void k_segred(const float* __restrict__ seg8, float* __restrict__ inv, int N)
{
    int i = blockIdx.x * 256 + threadIdx.x;
    if (i >= N * HEADS) return;
    float s = 0.f;
#pragma unroll
    for (int xcd = 0; xcd < NXCD; xcd++) s += seg8[(size_t)xcd * N * HEADS + i];
    inv[i] = 1.f / (s + 1e-16f);
}

// K5: out8[xcd][col,c] += (1/H)*sum_h alpha*xwh[row,c,h]; XCD-local L2 atomics
__global__ __launch_bounds__(256) void k_scatter(const int* __restrict__ ei, int E,
                                                 const float* __restrict__ ealpha,
                                                 const float* __restrict__ inv,
                                                 const unsigned short* __restrict__ xwh,
                                                 float* __restrict__ out8, int N)
{
    int xc = xcc_id();
    float* out_acc = out8 + (size_t)xc * N * CD;
    int t = threadIdx.x;
    int le = t >> 5, c = t & 31;
    int e = blockIdx.x * 8 + le;
    if (e >= E) return;
    int r = ei[e], cl = ei[E + e];
    int lane = t & 63;
    float av = 0.f;
    if (c < 4) av = ealpha[e * 4 + c] * inv[r * 4 + c];
    ushort4 p = ((const ushort4*)xwh)[(size_t)r * 32 + c];
    float a0 = __shfl(av, (lane & 32) + 0, 64);
    float a1 = __shfl(av, (lane & 32) + 1, 64);
    float a2 = __shfl(av, (lane & 32) + 2, 64);
    float a3 = __shfl(av, (lane & 32) + 3, 64);
    float v = a0 * bf2f(p.x) + a1 * bf2f(p.y) + a2 * bf2f(p.z) + a3 * bf2f(p.w);
    atomAddX(&out_acc[cl * CD + c], 0.25f * v);
}

// K6: out = sum_x out8[x] + bias
__global__ void k_final(const float4* __restrict__ out8, const float4* __restrict__ bias,
                        float4* __restrict__ out, int N)
{
    int i = blockIdx.x * 256 + threadIdx.x;
    if (i >= N * 8) return;
    float4 b = bias[i & 7];
    float4 s = make_float4(b.x, b.y, b.z, b.w);
#pragma unroll
    for (int xcd = 0; xcd < NXCD; xcd++) {
        float4 a = out8[(size_t)xcd * N * 8 + i];
        s.x += a.x; s.y += a.y; s.z += a.z; s.w += a.w;
    }
    out[i] = s;
}

extern "C" void kernel_launch(void* const* d_in, const int* in_sizes, int n_in,
                              void* d_out, int out_size, void* d_ws, size_t ws_size,
                              hipStream_t stream)
{
    const float* x    = (const float*)d_in[0];
    const int*   ei   = (const int*)d_in[1];
    const float* w    = (const float*)d_in[2];
    const float* att  = (const float*)d_in[3];
    const float* bias = (const float*)d_in[4];
    float* out = (float*)d_out;
    int N = in_sizes[0] / FDIM;
    int E = in_sizes[1] / 2;

    unsigned short* xwh = (unsigned short*)d_ws;            // N*128 bf16
    float* fws     = (float*)(xwh + (size_t)N * FDIM);
    float* a_src   = fws;                                   // N*4
    float* a_dst   = a_src + (size_t)N * HEADS;             // N*4
    float* inv     = a_dst + (size_t)N * HEADS;             // N*4
    float* ealpha  = inv + (size_t)N * HEADS;               // E*4
    float* seg8    = ealpha + (size_t)E * HEADS;            // 8*N*4
    float* out8    = seg8 + (size_t)NXCD * N * HEADS;       // 8*N*32 (contig after seg8)

    int nz4 = NXCD * N * 9;   // (seg8 + out8) float4 count = 8*N*36/4

    k_gemm<<<(N + BM - 1) / BM, 256, 0, stream>>>(x, w, xwh, N);
    k_logits<<<(N + 255) / 256, 256, 0, stream>>>(xwh, att, a_src, a_dst, N);
    k_init<<<(nz4 + 255) / 256, 256, 0, stream>>>((float4*)seg8, nz4);
    k_esum<<<(E * HEADS + 255) / 256, 256, 0, stream>>>(ei, E, a_src, a_dst, seg8, N, ealpha);
    k_segred<<<(N * HEADS + 255) / 256, 256, 0, stream>>>(seg8, inv, N);
    k_scatter<<<(E + 7) / 8, 256, 0, stream>>>(ei, E, ealpha, inv, xwh, out8, N);
    k_final<<<(N * 8 + 255) / 256, 256, 0, stream>>>((const float4*)out8, (const float4*)bias, (float4*)out, N);
}

// Round 7
// 214.103 us; speedup vs baseline: 1.2710x; 1.2710x over previous
//
#include <hip/hip_runtime.h>
#include <hip/hip_fp16.h>

#define FDIM 128
#define HEADS 4
#define CD 32
#define BM 64
#define XPAD 68

static __device__ __forceinline__ unsigned short f2bf(float v) {
    unsigned u = __float_as_uint(v);
    u += 0x7FFF + ((u >> 16) & 1);          // round-nearest-even
    return (unsigned short)(u >> 16);
}
static __device__ __forceinline__ float bf2f(unsigned short u) {
    return __uint_as_float(((unsigned)u) << 16);
}

// K1: xwh[n][c][h] (bf16) = row-tile of x @ W. x-tile in LDS, W from L2.
// Prologue also zeroes out_acc2 (fp16, N*32) and seg (N*4) via grid-stride.
__global__ __launch_bounds__(256) void k_gemm(const float* __restrict__ x,
                                              const float* __restrict__ w,
                                              unsigned short* __restrict__ xwh,
                                              float4* __restrict__ zero_base,
                                              int nz4, int N)
{
    __shared__ float xs[FDIM * XPAD];    // [k][row]
    int t = threadIdx.x;
    int row0 = blockIdx.x * BM;
    // zero accumulators (independent of this block's GEMM work)
    for (int i = blockIdx.x * 256 + t; i < nz4; i += gridDim.x * 256)
        zero_base[i] = make_float4(0.f, 0.f, 0.f, 0.f);
#pragma unroll
    for (int it = 0; it < 8; it++) {
        int i = t + 256 * it;
        int row = i & 63, kq = i >> 6;
        float4 v = make_float4(0.f, 0.f, 0.f, 0.f);
        if (row0 + row < N) v = ((const float4*)x)[(size_t)(row0 + row) * 32 + kq];
        xs[(kq * 4 + 0) * XPAD + row] = v.x;
        xs[(kq * 4 + 1) * XPAD + row] = v.y;
        xs[(kq * 4 + 2) * XPAD + row] = v.z;
        xs[(kq * 4 + 3) * XPAD + row] = v.w;
    }
    __syncthreads();
    int tx = t & 31, ty = t >> 5;
    int c0 = tx * 4, r0 = ty * 8;
    const float4* w4 = (const float4*)w;
    float acc[8][4];
#pragma unroll
    for (int i = 0; i < 8; i++)
#pragma unroll
        for (int j = 0; j < 4; j++) acc[i][j] = 0.f;
#pragma unroll 4
    for (int k = 0; k < FDIM; k++) {
        float4 wv = w4[k * 32 + tx];
        float4 xa = *(const float4*)&xs[k * XPAD + r0];
        float4 xb = *(const float4*)&xs[k * XPAD + r0 + 4];
        float xr[8] = {xa.x, xa.y, xa.z, xa.w, xb.x, xb.y, xb.z, xb.w};
        float wr[4] = {wv.x, wv.y, wv.z, wv.w};
#pragma unroll
        for (int i = 0; i < 8; i++)
#pragma unroll
            for (int j = 0; j < 4; j++) acc[i][j] += xr[i] * wr[j];
    }
    int h = c0 >> 5, chb = c0 & 31;
#pragma unroll
    for (int i = 0; i < 8; i++) {
        int r = row0 + r0 + i;
        if (r < N) {
#pragma unroll
            for (int j = 0; j < 4; j++)
                xwh[(size_t)r * FDIM + (chb + j) * 4 + h] = f2bf(acc[i][j]);
        }
    }
}

// K2: per-node half-logits
__global__ __launch_bounds__(256) void k_logits(const unsigned short* __restrict__ xwh,
                                                const float* __restrict__ att,
                                                float* __restrict__ a_src,
                                                float* __restrict__ a_dst, int N)
{
    __shared__ float attl[HEADS * 2 * CD];
    int t = threadIdx.x;
    attl[t] = att[t];
    __syncthreads();
    int n = blockIdx.x * 256 + t;
    if (n >= N) return;
    const ushort4* xp = (const ushort4*)(xwh + (size_t)n * FDIM);
    float s[4] = {0.f, 0.f, 0.f, 0.f}, d[4] = {0.f, 0.f, 0.f, 0.f};
#pragma unroll 8
    for (int c = 0; c < CD; c++) {
        ushort4 p = xp[c];
        float f0 = bf2f(p.x), f1 = bf2f(p.y), f2 = bf2f(p.z), f3 = bf2f(p.w);
        s[0] += f0 * attl[0 * 64 + c];  d[0] += f0 * attl[0 * 64 + 32 + c];
        s[1] += f1 * attl[1 * 64 + c];  d[1] += f1 * attl[1 * 64 + 32 + c];
        s[2] += f2 * attl[2 * 64 + c];  d[2] += f2 * attl[2 * 64 + 32 + c];
        s[3] += f3 * attl[3 * 64 + c];  d[3] += f3 * attl[3 * 64 + 32 + c];
    }
    *(float4*)&a_src[n * 4] = make_float4(s[0], s[1], s[2], s[3]);
    *(float4*)&a_dst[n * 4] = make_float4(d[0], d[1], d[2], d[3]);
}

// K4: seg[row,h] += exp(leaky(...)); 4 adjacent lanes share one 16B sector
__global__ __launch_bounds__(256) void k_esum(const int* __restrict__ ei, int E,
                                              const float* __restrict__ a_src,
                                              const float* __restrict__ a_dst,
                                              float* __restrict__ seg,
                                              float* __restrict__ ealpha)
{
    int gid = blockIdx.x * 256 + threadIdx.x;
    if (gid >= E * HEADS) return;
    int e = gid >> 2, h = gid & 3;
    int r = ei[e], cl = ei[E + e];
    float a = a_src[r * 4 + h] + a_dst[cl * 4 + h];
    a = a >= 0.f ? a : 0.2f * a;
    float ex = __expf(a);
    ealpha[gid] = ex;
    atomicAdd(&seg[r * 4 + h], ex);
}

// K5: out_acc2[col][c2] (+= packed fp16 pair) — 16 lanes per edge, one
// global_atomic_pk_add_f16 per lane: 16 atomic dwords/edge instead of 32.
__global__ __launch_bounds__(256) void k_scatter(const int* __restrict__ ei, int E,
                                                 const float* __restrict__ ealpha,
                                                 const float* __restrict__ seg,
                                                 const unsigned short* __restrict__ xwh,
                                                 __half2* __restrict__ out_acc2)
{
    int t = threadIdx.x;
    int le = t >> 4, c2 = t & 15;        // 16 edges/block, lane pair-channel
    int e = blockIdx.x * 16 + le;
    if (e >= E) return;
    int r = ei[e], cl = ei[E + e];
    int lane = t & 63;
    float av = 0.f;
    if (c2 < 4) av = 0.25f * ealpha[e * 4 + c2] / (seg[r * 4 + c2] + 1e-16f);
    // xwh[r][2c2..2c2+1][0..3] = 8 bf16 = 16 B
    uint4 q = ((const uint4*)(xwh + (size_t)r * FDIM))[c2];
    float a0 = __shfl(av, (lane & 48) + 0, 64);
    float a1 = __shfl(av, (lane & 48) + 1, 64);
    float a2 = __shfl(av, (lane & 48) + 2, 64);
    float a3 = __shfl(av, (lane & 48) + 3, 64);
    float v0 = a0 * bf2f((unsigned short)(q.x & 0xFFFF)) + a1 * bf2f((unsigned short)(q.x >> 16))
             + a2 * bf2f((unsigned short)(q.y & 0xFFFF)) + a3 * bf2f((unsigned short)(q.y >> 16));
    float v1 = a0 * bf2f((unsigned short)(q.z & 0xFFFF)) + a1 * bf2f((unsigned short)(q.z >> 16))
             + a2 * bf2f((unsigned short)(q.w & 0xFFFF)) + a3 * bf2f((unsigned short)(q.w >> 16));
    unsafeAtomicAdd(&out_acc2[(size_t)cl * 16 + c2], __floats2half2_rn(v0, v1));
}

// K6: out = fp16 out_acc2 + bias  (one thread per 4 channels)
__global__ void k_final(const __half2* __restrict__ out_acc2, const float4* __restrict__ bias,
                        float4* __restrict__ out, int N)
{
    int i = blockIdx.x * 256 + threadIdx.x;
    if (i >= N * 8) return;
    float4 b = bias[i & 7];
    float2 f0 = __half22float2(out_acc2[i * 2]);
    float2 f1 = __half22float2(out_acc2[i * 2 + 1]);
    out[i] = make_float4(f0.x + b.x, f0.y + b.y, f1.x + b.z, f1.y + b.w);
}

extern "C" void kernel_launch(void* const* d_in, const int* in_sizes, int n_in,
                              void* d_out, int out_size, void* d_ws, size_t ws_size,
                              hipStream_t stream)
{
    const float* x    = (const float*)d_in[0];
    const int*   ei   = (const int*)d_in[1];
    const float* w    = (const float*)d_in[2];
    const float* att  = (const float*)d_in[3];
    const float* bias = (const float*)d_in[4];
    float* out = (float*)d_out;
    int N = in_sizes[0] / FDIM;
    int E = in_sizes[1] / 2;

    unsigned short* xwh = (unsigned short*)d_ws;            // N*128 bf16
    float* fws      = (float*)(xwh + (size_t)N * FDIM);
    float* a_src    = fws;                                  // N*4
    float* a_dst    = a_src + (size_t)N * HEADS;            // N*4
    float* ealpha   = a_dst + (size_t)N * HEADS;            // E*4
    float* seg      = ealpha + (size_t)E * HEADS;           // N*4     (zeroed)
    __half2* out_acc2 = (__half2*)(seg + (size_t)N * HEADS); // N*16 half2 (zeroed, contig after seg)

    int nz4 = (N * HEADS + N * CD / 2 + 3) / 4;   // seg floats + out_acc2 (half2==1 float each)

    k_gemm<<<(N + BM - 1) / BM, 256, 0, stream>>>(x, w, xwh, (float4*)seg, nz4, N);
    k_logits<<<(N + 255) / 256, 256, 0, stream>>>(xwh, att, a_src, a_dst, N);
    k_esum<<<(E * HEADS + 255) / 256, 256, 0, stream>>>(ei, E, a_src, a_dst, seg, ealpha);
    k_scatter<<<(E + 15) / 16, 256, 0, stream>>>(ei, E, ealpha, seg, xwh, out_acc2);
    k_final<<<(N * 8 + 255) / 256, 256, 0, stream>>>(out_acc2, (const float4*)bias, (float4*)out, N);
}

// Round 8
// 210.162 us; speedup vs baseline: 1.2948x; 1.0187x over previous
//
#include <hip/hip_runtime.h>
#include <hip/hip_fp16.h>

#define FDIM 128
#define HEADS 4
#define CD 32
#define BM 64
#define XPAD 68

static __device__ __forceinline__ unsigned short f2bf(float v) {
    unsigned u = __float_as_uint(v);
    u += 0x7FFF + ((u >> 16) & 1);          // round-nearest-even
    return (unsigned short)(u >> 16);
}
static __device__ __forceinline__ float bf2f(unsigned short u) {
    return __uint_as_float(((unsigned)u) << 16);
}

// K1: fused GEMM + logits.
//  xwh[n][c][h] (bf16) = row-tile of x @ W   (x-tile in LDS, W from L2)
//  a_src/a_dst[n][h] = per-node attention half-logits (acc round-trips LDS)
//  prologue zeroes seg + out_acc2 via grid-stride.
__global__ __launch_bounds__(256) void k_gemm(const float* __restrict__ x,
                                              const float* __restrict__ w,
                                              const float* __restrict__ att,
                                              unsigned short* __restrict__ xwh,
                                              float* __restrict__ a_src,
                                              float* __restrict__ a_dst,
                                              float4* __restrict__ zero_base,
                                              int nz4, int N)
{
    __shared__ float xs[FDIM * XPAD];    // staging [k][row]; later acc [row][132]
    __shared__ float attl[HEADS * 2 * CD];
    int t = threadIdx.x;
    int row0 = blockIdx.x * BM;
    // zero accumulators (independent of this block's GEMM work)
    for (int i = blockIdx.x * 256 + t; i < nz4; i += gridDim.x * 256)
        zero_base[i] = make_float4(0.f, 0.f, 0.f, 0.f);
    attl[t] = att[t];
#pragma unroll
    for (int it = 0; it < 8; it++) {
        int i = t + 256 * it;
        int row = i & 63, kq = i >> 6;
        float4 v = make_float4(0.f, 0.f, 0.f, 0.f);
        if (row0 + row < N) v = ((const float4*)x)[(size_t)(row0 + row) * 32 + kq];
        xs[(kq * 4 + 0) * XPAD + row] = v.x;
        xs[(kq * 4 + 1) * XPAD + row] = v.y;
        xs[(kq * 4 + 2) * XPAD + row] = v.z;
        xs[(kq * 4 + 3) * XPAD + row] = v.w;
    }
    __syncthreads();
    int tx = t & 31, ty = t >> 5;
    int c0 = tx * 4, r0 = ty * 8;
    const float4* w4 = (const float4*)w;
    float acc[8][4];
#pragma unroll
    for (int i = 0; i < 8; i++)
#pragma unroll
        for (int j = 0; j < 4; j++) acc[i][j] = 0.f;
#pragma unroll 4
    for (int k = 0; k < FDIM; k++) {
        float4 wv = w4[k * 32 + tx];
        float4 xa = *(const float4*)&xs[k * XPAD + r0];
        float4 xb = *(const float4*)&xs[k * XPAD + r0 + 4];
        float xr[8] = {xa.x, xa.y, xa.z, xa.w, xb.x, xb.y, xb.z, xb.w};
        float wr[4] = {wv.x, wv.y, wv.z, wv.w};
#pragma unroll
        for (int i = 0; i < 8; i++)
#pragma unroll
            for (int j = 0; j < 4; j++) acc[i][j] += xr[i] * wr[j];
    }
    // global store: bf16 head-interleaved  xwh[r*128 + ch*4 + h]
    int h0 = c0 >> 5, chb = c0 & 31;
#pragma unroll
    for (int i = 0; i < 8; i++) {
        int r = row0 + r0 + i;
        if (r < N) {
#pragma unroll
            for (int j = 0; j < 4; j++)
                xwh[(size_t)r * FDIM + (chb + j) * 4 + h0] = f2bf(acc[i][j]);
        }
    }
    __syncthreads();                       // xs staging no longer needed
    // round-trip acc through LDS: accs[row][col], row stride 132 (64*132=8448 <= 8704)
    float* accs = xs;
#pragma unroll
    for (int i = 0; i < 8; i++)
        *(float4*)&accs[(r0 + i) * 132 + c0] =
            make_float4(acc[i][0], acc[i][1], acc[i][2], acc[i][3]);
    __syncthreads();
    // logits: 4 lanes per row, lane handles one head (cols h*32..h*32+31)
    int row = t >> 2, h = t & 3;
    const float* ap = &attl[h * 2 * CD];
    const float* xr = &accs[row * 132 + h * CD];
    float s = 0.f, d = 0.f;
#pragma unroll 8
    for (int c = 0; c < CD; c++) { float v = xr[c]; s += v * ap[c]; d += v * ap[CD + c]; }
    int n = row0 + row;
    if (n < N) { a_src[n * 4 + h] = s; a_dst[n * 4 + h] = d; }
}

// K4: seg[row,h] += exp(leaky(...)); 4 adjacent lanes share one 16B sector.
// ealpha stored fp16 (coalesced).
__global__ __launch_bounds__(256) void k_esum(const int* __restrict__ ei, int E,
                                              const float* __restrict__ a_src,
                                              const float* __restrict__ a_dst,
                                              float* __restrict__ seg,
                                              __half* __restrict__ ealpha)
{
    int gid = blockIdx.x * 256 + threadIdx.x;
    if (gid >= E * HEADS) return;
    int e = gid >> 2, h = gid & 3;
    int r = ei[e], cl = ei[E + e];
    float a = a_src[r * 4 + h] + a_dst[cl * 4 + h];
    a = a >= 0.f ? a : 0.2f * a;
    float ex = __expf(a);
    ealpha[gid] = __float2half(ex);
    atomicAdd(&seg[r * 4 + h], ex);
}

// K5: out_acc2[col][c2] += packed fp16 pair — 16 lanes/edge, one
// global_atomic_pk_add_f16 per lane (64 B atomic footprint per edge).
__global__ __launch_bounds__(256) void k_scatter(const int* __restrict__ ei, int E,
                                                 const __half* __restrict__ ealpha,
                                                 const float* __restrict__ seg,
                                                 const unsigned short* __restrict__ xwh,
                                                 __half2* __restrict__ out_acc2)
{
    int t = threadIdx.x;
    int le = t >> 4, c2 = t & 15;        // 16 edges/block
    int e = blockIdx.x * 16 + le;
    if (e >= E) return;
    int r = ei[e], cl = ei[E + e];
    int lane = t & 63;
    float av = 0.f;
    if (c2 < 4) av = 0.25f * __half2float(ealpha[e * 4 + c2]) / (seg[r * 4 + c2] + 1e-16f);
    // xwh[r][2c2..2c2+1][0..3] = 8 bf16 = 16 B
    uint4 q = ((const uint4*)(xwh + (size_t)r * FDIM))[c2];
    float a0 = __shfl(av, (lane & 48) + 0, 64);
    float a1 = __shfl(av, (lane & 48) + 1, 64);
    float a2 = __shfl(av, (lane & 48) + 2, 64);
    float a3 = __shfl(av, (lane & 48) + 3, 64);
    float v0 = a0 * bf2f((unsigned short)(q.x & 0xFFFF)) + a1 * bf2f((unsigned short)(q.x >> 16))
             + a2 * bf2f((unsigned short)(q.y & 0xFFFF)) + a3 * bf2f((unsigned short)(q.y >> 16));
    float v1 = a0 * bf2f((unsigned short)(q.z & 0xFFFF)) + a1 * bf2f((unsigned short)(q.z >> 16))
             + a2 * bf2f((unsigned short)(q.w & 0xFFFF)) + a3 * bf2f((unsigned short)(q.w >> 16));
    unsafeAtomicAdd(&out_acc2[(size_t)cl * 16 + c2], __floats2half2_rn(v0, v1));
}

// K6: out = fp16 out_acc2 + bias
__global__ void k_final(const __half2* __restrict__ out_acc2, const float4* __restrict__ bias,
                        float4* __restrict__ out, int N)
{
    int i = blockIdx.x * 256 + threadIdx.x;
    if (i >= N * 8) return;
    float4 b = bias[i & 7];
    float2 f0 = __half22float2(out_acc2[i * 2]);
    float2 f1 = __half22float2(out_acc2[i * 2 + 1]);
    out[i] = make_float4(f0.x + b.x, f0.y + b.y, f1.x + b.z, f1.y + b.w);
}

extern "C" void kernel_launch(void* const* d_in, const int* in_sizes, int n_in,
                              void* d_out, int out_size, void* d_ws, size_t ws_size,
                              hipStream_t stream)
{
    const float* x    = (const float*)d_in[0];
    const int*   ei   = (const int*)d_in[1];
    const float* w    = (const float*)d_in[2];
    const float* att  = (const float*)d_in[3];
    const float* bias = (const float*)d_in[4];
    float* out = (float*)d_out;
    int N = in_sizes[0] / FDIM;
    int E = in_sizes[1] / 2;

    unsigned short* xwh = (unsigned short*)d_ws;              // N*128 bf16  (12.8 MB)
    float* fws      = (float*)(xwh + (size_t)N * FDIM);
    float* a_src    = fws;                                    // N*4 f32
    float* a_dst    = a_src + (size_t)N * HEADS;              // N*4 f32
    float* seg      = a_dst + (size_t)N * HEADS;              // N*4 f32   (zeroed)
    __half2* out_acc2 = (__half2*)(seg + (size_t)N * HEADS);  // N*16 half2 (zeroed, contig)
    __half* ealpha  = (__half*)(out_acc2 + (size_t)N * 16);   // E*4 fp16

    int nz4 = N * 5;   // (seg: N*4 floats + out_acc2: N*16 half2 == N*16 floats) / 4

    k_gemm<<<(N + BM - 1) / BM, 256, 0, stream>>>(x, w, att, xwh, a_src, a_dst,
                                                  (float4*)seg, nz4, N);
    k_esum<<<(E * HEADS + 255) / 256, 256, 0, stream>>>(ei, E, a_src, a_dst, seg, ealpha);
    k_scatter<<<(E + 15) / 16, 256, 0, stream>>>(ei, E, ealpha, seg, xwh, out_acc2);
    k_final<<<(N * 8 + 255) / 256, 256, 0, stream>>>(out_acc2, (const float4*)bias, (float4*)out, N);
}